// Round 8
// baseline (417.614 us; speedup 1.0000x reference)
//
#include <hip/hip_runtime.h>
#include <hip/hip_cooperative_groups.h>

namespace cg = cooperative_groups;

// qkv: (4, 8192, 3, 16, 64) f32 ; out: (4, 8192, 16, 64) f32
constexpr int   Bn    = 4;
constexpr int   Nn    = 8192;
constexpr int   Hn    = 16;
constexpr int   Dn    = 64;
constexpr int   ROW   = 3 * Hn * Dn;                   // 3072 floats = 12 KB
constexpr long long QKV_B = (long long)Nn * ROW;       // 25165824
constexpr int   OUT_N = Hn * Dn;                       // 1024
constexpr long long OUT_B = (long long)Nn * OUT_N;     // 8388608
constexpr long long OUT_TOT = (long long)Bn * OUT_B;   // 33554432
constexpr int   NBLK  = 2048;                          // fallback dil_main grid
constexpr int   BLKS_PER_B = 512;
constexpr int   UNITS = 1024;                          // fused: (b, 8-j chunk)

using v4f = __attribute__((ext_vector_type(4))) float;
using v4u = __attribute__((ext_vector_type(4))) unsigned int;

template<int CTRL>
__device__ __forceinline__ float dpp_add(float x) {
  int mv = __builtin_amdgcn_update_dpp(0, __float_as_int(x), CTRL, 0xF, 0xF, true);
  return x + __int_as_float(mv);
}
__device__ __forceinline__ float row16_sum(float x) {
  x = dpp_add<0xB1>(x);
  x = dpp_add<0x4E>(x);
  x = dpp_add<0x124>(x);
  x = dpp_add<0x128>(x);
  return x;
}

__device__ __forceinline__ unsigned short f2bf_rne(float x) {
  unsigned u = __float_as_uint(x);
  u += 0x7FFFu + ((u >> 16) & 1u);
  return (unsigned short)(u >> 16);
}
__device__ __forceinline__ float bf2f(unsigned short u) {
  return __uint_as_float(((unsigned)u) << 16);
}

struct Frag {
  float q[4][4], k[4][4], v[4][4];
};

__device__ __forceinline__ void load_frag(Frag& f, const float* __restrict__ qb,
                                          int j) {
#pragma unroll
  for (int m = 0; m < 4; ++m) {
    const float* rp = qb + (size_t)(m * 2048 + j) * ROW;
    float4 t;
    t = *(const float4*)(rp);
    f.q[m][0] = t.x; f.q[m][1] = t.y; f.q[m][2] = t.z; f.q[m][3] = t.w;
    t = *(const float4*)(rp + 1024);
    f.k[m][0] = t.x; f.k[m][1] = t.y; f.k[m][2] = t.z; f.k[m][3] = t.w;
    t = *(const float4*)(rp + 2048);
    f.v[m][0] = t.x; f.v[m][1] = t.y; f.v[m][2] = t.z; f.v[m][3] = t.w;
  }
}

template<bool USE_BF16>
__device__ __forceinline__ void compute_frag(const Frag& f, int j, size_t obase,
                                             float* __restrict__ out,
                                             unsigned short* __restrict__ ws16,
                                             float* cs) {
  float S[4][4];
#pragma unroll
  for (int m = 0; m < 4; ++m)
#pragma unroll
    for (int m2 = 0; m2 < 4; ++m2) {
      float s = f.q[m][0] * f.k[m2][0] + f.q[m][1] * f.k[m2][1] +
                f.q[m][2] * f.k[m2][2] + f.q[m][3] * f.k[m2][3];
      S[m][m2] = row16_sum(s) * 0.125f;   // 1/sqrt(64)
    }

  float acc[4][4];

  // branch 1 (r=1)
#pragma unroll
  for (int m = 0; m < 4; ++m) {
    float mx = fmaxf(fmaxf(S[m][0], S[m][1]), fmaxf(S[m][2], S[m][3]));
    float e0 = __expf(S[m][0] - mx);
    float e1 = __expf(S[m][1] - mx);
    float e2 = __expf(S[m][2] - mx);
    float e3 = __expf(S[m][3] - mx);
    float inv = 1.0f / (e0 + e1 + e2 + e3);
    e0 *= inv; e1 *= inv; e2 *= inv; e3 *= inv;
#pragma unroll
    for (int c = 0; c < 4; ++c)
      acc[m][c] = e0 * f.v[0][c] + e1 * f.v[1][c] +
                  e2 * f.v[2][c] + e3 * f.v[3][c];
  }

  // branch 2 (r=2): iff j even (block-uniform)
  if ((j & 1) == 0) {
#pragma unroll
    for (int m = 0; m < 4; ++m) {
      const int a  = m & 1;
      const int b2 = a + 2;
      float sa = S[m][a], sb = S[m][b2];
      float mx = fmaxf(sa, sb);
      float ea = __expf(sa - mx);
      float eb = __expf(sb - mx);
      float inv = 1.0f / (ea + eb);
      ea *= inv; eb *= inv;
#pragma unroll
      for (int c = 0; c < 4; ++c)
        acc[m][c] += ea * f.v[a][c] + eb * f.v[b2][c];
    }
  }

  // branch 3 (r=4): iff j % 4 == 0 (block-uniform)
  if ((j & 3) == 0) {
#pragma unroll
    for (int m = 0; m < 4; ++m)
#pragma unroll
      for (int c = 0; c < 4; ++c)
        acc[m][c] += f.v[m][c];
  }

#pragma unroll
  for (int m = 0; m < 4; ++m) {
    const size_t oi = obase + (size_t)(m * 2048 + j) * OUT_N;
    if (USE_BF16) {
      ushort4 st;
      st.x = f2bf_rne(acc[m][0]); st.y = f2bf_rne(acc[m][1]);
      st.z = f2bf_rne(acc[m][2]); st.w = f2bf_rne(acc[m][3]);
      *(ushort4*)(ws16 + oi) = st;
    } else {
      *(float4*)(out + oi) =
          make_float4(acc[m][0], acc[m][1], acc[m][2], acc[m][3]);
    }
    cs[0] += acc[m][0]; cs[1] += acc[m][1];
    cs[2] += acc[m][2]; cs[3] += acc[m][3];
  }
}

// ============ FUSED cooperative kernel: attention + colsum + scale ============
// unit = (b, chunk of 8 consecutive j) : 1024 units, grid-uniform.
// phase 1: compute unnormalized out (bf16 in ws16) + per-unit colsum partials
// phase 2: one wave per (b,h,d) column reduces 256 unit-partials -> recip
// phase 3: each block rescales the SAME region it wrote (L2/L3-hot reads)
template<bool USE_BF16>
__global__ __launch_bounds__(256) void dil_fused(const float* __restrict__ qkv,
                                                 float* __restrict__ out,
                                                 unsigned short* __restrict__ ws16,
                                                 float* __restrict__ partial,
                                                 float* __restrict__ recip,
                                                 int unitsPerBlk) {
  cg::grid_group grid = cg::this_grid();
  const int tid = threadIdx.x;

  // ---------------- phase 1 ----------------
  for (int uu = 0; uu < unitsPerBlk; ++uu) {
    const int unit = blockIdx.x * unitsPerBlk + uu;   // 0..1023
    const int b    = unit >> 8;
    const int j0   = (unit & 255) * 8;
    const float* qb = qkv + (size_t)b * QKV_B + tid * 4;
    const size_t obase = (size_t)b * OUT_B + tid * 4;
    float cs[4] = {0.f, 0.f, 0.f, 0.f};
    for (int it = 0; it < 8; ++it) {
      Frag f;
      load_frag(f, qb, j0 + it);
      compute_frag<USE_BF16>(f, j0 + it, obase, out, ws16, cs);
    }
    *(float4*)(partial + (size_t)unit * 1024 + tid * 4) =
        make_float4(cs[0], cs[1], cs[2], cs[3]);
  }

  __threadfence();
  grid.sync();

  // ---------------- phase 2: recip ----------------
  // column = (b, w) of 4096; 256 unit-rows per b; one wave per column.
  {
    const int nWaves = (gridDim.x * 256) >> 6;
    const int waveId = (blockIdx.x * 256 + tid) >> 6;
    const int lane   = tid & 63;
    for (int col = waveId; col < 4096; col += nWaves) {
      const int b = col >> 10;
      const int w = col & 1023;
      const float* p = partial + (size_t)(b * 256) * 1024 + w;
      double s = 0.0;
#pragma unroll
      for (int i = 0; i < 4; ++i)
        s += (double)p[(size_t)(lane * 4 + i) * 1024];
#pragma unroll
      for (int off = 32; off; off >>= 1)
        s += __shfl_xor(s, off, 64);
      if (lane == 0) recip[col] = (float)(1.0 / s);
    }
  }

  __threadfence();
  grid.sync();

  // ---------------- phase 3: scale own units ----------------
  for (int uu = 0; uu < unitsPerBlk; ++uu) {
    const int unit = blockIdx.x * unitsPerBlk + uu;
    const int b    = unit >> 8;
    const int j0   = (unit & 255) * 8;
    const size_t obase = (size_t)b * OUT_B + tid * 4;
    const float4 r = *(const float4*)(recip + b * 1024 + tid * 4);
    for (int it = 0; it < 8; ++it) {
      const int j = j0 + it;
#pragma unroll
      for (int m = 0; m < 4; ++m) {
        const size_t oi = obase + (size_t)(m * 2048 + j) * OUT_N;
        float4 o;
        if (USE_BF16) {
          const ushort4 raw = *(const ushort4*)(ws16 + oi);
          o.x = bf2f(raw.x) * r.x;
          o.y = bf2f(raw.y) * r.y;
          o.z = bf2f(raw.z) * r.z;
          o.w = bf2f(raw.w) * r.w;
        } else {
          o = *(const float4*)(out + oi);
          o.x *= r.x; o.y *= r.y; o.z *= r.z; o.w *= r.w;
        }
        *(float4*)(out + oi) = o;
      }
    }
  }
}

// ===================== fallback 3-kernel path (R7) =====================
template<bool USE_BF16>
__global__ __launch_bounds__(256) void dil_main(const float* __restrict__ qkv,
                                                float* __restrict__ out,
                                                unsigned short* __restrict__ ws16,
                                                float* __restrict__ partial) {
  const int tid  = threadIdx.x;
  const int bid  = blockIdx.x;        // 0..2047
  const int b    = bid >> 9;
  const int j0   = (bid & 511) * 4;

  const float* qb = qkv + (size_t)b * QKV_B + tid * 4;
  const size_t obase = (size_t)b * OUT_B + tid * 4;

  float cs[4] = {0.f, 0.f, 0.f, 0.f};

  Frag A, B;
  load_frag(A, qb, j0);
  load_frag(B, qb, j0 + 1);
  compute_frag<USE_BF16>(A, j0, obase, out, ws16, cs);
  load_frag(A, qb, j0 + 2);
  compute_frag<USE_BF16>(B, j0 + 1, obase, out, ws16, cs);
  load_frag(B, qb, j0 + 3);
  compute_frag<USE_BF16>(A, j0 + 2, obase, out, ws16, cs);
  compute_frag<USE_BF16>(B, j0 + 3, obase, out, ws16, cs);

  *(float4*)(partial + (size_t)bid * 1024 + tid * 4) =
      make_float4(cs[0], cs[1], cs[2], cs[3]);
}

__global__ __launch_bounds__(256) void dil_recip(const float* __restrict__ partial,
                                                 float* __restrict__ recip) {
  const int i = blockIdx.x * 256 + threadIdx.x;   // 0..4095
  const int b = i >> 10;
  const int w = i & 1023;
  const float* p = partial + (size_t)b * BLKS_PER_B * 1024 + w;
  double s = 0.0;
  for (int r = 0; r < BLKS_PER_B; ++r)
    s += (double)p[(size_t)r * 1024];
  recip[i] = (float)(1.0 / s);
}

__global__ __launch_bounds__(256) void dil_scale_bf16(const unsigned short* __restrict__ ws16,
                                                      float* __restrict__ out,
                                                      const float* __restrict__ recip) {
  const long long u = (long long)blockIdx.x * 256 + threadIdx.x;
  const long long e = u * 8;
  const int b  = (int)(e >> 23);
  const int h  = (int)((e >> 6) & 15);
  const int q8 = (int)((e >> 3) & 7);

  const float4 r0 = ((const float4*)recip)[((b * 16 + h) << 4) + q8 * 2];
  const float4 r1 = ((const float4*)recip)[((b * 16 + h) << 4) + q8 * 2 + 1];

  const v4u raw = __builtin_nontemporal_load((const v4u*)(ws16 + e));
  v4f o0, o1;
  o0[0] = __uint_as_float((raw[0] & 0xFFFFu) << 16) * r0.x;
  o0[1] = __uint_as_float((raw[0] & 0xFFFF0000u))   * r0.y;
  o0[2] = __uint_as_float((raw[1] & 0xFFFFu) << 16) * r0.z;
  o0[3] = __uint_as_float((raw[1] & 0xFFFF0000u))   * r0.w;
  o1[0] = __uint_as_float((raw[2] & 0xFFFFu) << 16) * r1.x;
  o1[1] = __uint_as_float((raw[2] & 0xFFFF0000u))   * r1.y;
  o1[2] = __uint_as_float((raw[3] & 0xFFFFu) << 16) * r1.z;
  o1[3] = __uint_as_float((raw[3] & 0xFFFF0000u))   * r1.w;
  __builtin_nontemporal_store(o0, (v4f*)(out + e));
  __builtin_nontemporal_store(o1, (v4f*)(out + e + 4));
}

__global__ __launch_bounds__(256) void dil_scale_f32(float* __restrict__ out,
                                                     const float* __restrict__ recip) {
  const long long f = (long long)blockIdx.x * 256 + threadIdx.x;
  const int d4 = (int)(f & 15);
  const int h  = (int)((f >> 4) & 15);
  const int b  = (int)(f >> 21);
  const float4 r = ((const float4*)recip)[(b * 16 + h) * 16 + d4];
  float4 o = ((const float4*)out)[f];
  o.x *= r.x; o.y *= r.y; o.z *= r.z; o.w *= r.w;
  ((float4*)out)[f] = o;
}

extern "C" void kernel_launch(void* const* d_in, const int* in_sizes, int n_in,
                              void* d_out, int out_size, void* d_ws, size_t ws_size,
                              hipStream_t stream) {
  const float* qkv = (const float*)d_in[0];
  float* out = (float*)d_out;

  const size_t bf16_bytes    = (size_t)OUT_TOT * 2;            // 67108864
  const size_t partialF_bytes = (size_t)UNITS * 1024 * 4;      // 4 MB (fused)
  const size_t partialK_bytes = (size_t)NBLK * 1024 * 4;       // 8 MB (fallback)
  const size_t recip_bytes   = 4096 * sizeof(float);

  // ---- try the fused cooperative path ----
  int dev = 0;
  hipGetDevice(&dev);
  int coop = 0;
  hipDeviceGetAttribute(&coop, hipDeviceAttributeCooperativeLaunch, dev);
  int numCU = 0;
  hipDeviceGetAttribute(&numCU, hipDeviceAttributeMultiprocessorCount, dev);
  int occ = 0;
  hipOccupancyMaxActiveBlocksPerMultiprocessor(&occ, dil_fused<true>, 256, 0);

  const bool ws_ok_fused =
      (bf16_bytes + partialF_bytes + recip_bytes) <= ws_size;
  const int maxResident = occ * numCU;
  int G = 0;
  if (maxResident >= 1024) G = 1024;
  else if (maxResident >= 512) G = 512;
  else if (maxResident >= 256) G = 256;

  if (coop && ws_ok_fused && G > 0) {
    unsigned short* ws16 = (unsigned short*)d_ws;
    float* partial = (float*)((char*)d_ws + bf16_bytes);
    float* recip   = (float*)((char*)d_ws + bf16_bytes + partialF_bytes);
    int upb = UNITS / G;
    void* args[] = {(void*)&qkv, (void*)&out, (void*)&ws16,
                    (void*)&partial, (void*)&recip, (void*)&upb};
    hipLaunchCooperativeKernel(reinterpret_cast<const void*>(&dil_fused<true>),
                               dim3(G), dim3(256), args, 0, stream);
    return;
  }

  // ---- fallback: proven 3-kernel path ----
  bool use_bf16 = (bf16_bytes + partialK_bytes + recip_bytes) <= ws_size;
  unsigned short* ws16 = (unsigned short*)d_ws;
  char* tail = (char*)d_ws + (use_bf16 ? bf16_bytes : 0);
  float* partial = (float*)tail;
  float* recip   = (float*)(tail + partialK_bytes);

  if (use_bf16)
    dil_main<true><<<NBLK, 256, 0, stream>>>(qkv, out, ws16, partial);
  else
    dil_main<false><<<NBLK, 256, 0, stream>>>(qkv, out, ws16, partial);

  dil_recip<<<16, 256, 0, stream>>>(partial, recip);

  if (use_bf16) {
    const long long nu = OUT_TOT / 8;
    dil_scale_bf16<<<(int)(nu / 256), 256, 0, stream>>>(ws16, out, recip);
  } else {
    const long long nf4 = OUT_TOT / 4;
    dil_scale_f32<<<(int)(nf4 / 256), 256, 0, stream>>>(out, recip);
  }
}

// Round 9
// 152.134 us; speedup vs baseline: 2.7450x; 2.7450x over previous
//
#include <hip/hip_runtime.h>

// qkv: (4, 8192, 3, 16, 64) f32 ; out: (4, 8192, 16, 64) f32
constexpr int   Bn    = 4;
constexpr int   Nn    = 8192;
constexpr int   Hn    = 16;
constexpr int   Dn    = 64;
constexpr int   ROW   = 3 * Hn * Dn;                   // 3072 floats = 12 KB
constexpr long long QKV_B = (long long)Nn * ROW;       // 25165824
constexpr int   OUT_N = Hn * Dn;                       // 1024
constexpr long long OUT_B = (long long)Nn * OUT_N;     // 8388608
constexpr long long OUT_TOT = (long long)Bn * OUT_B;   // 33554432
constexpr int   NBLK  = 2048;                          // dil_main grid
constexpr int   BLKS_PER_B = 512;

using v4f = __attribute__((ext_vector_type(4))) float;
using v4u = __attribute__((ext_vector_type(4))) unsigned int;

// x + dpp_move(x): fuses to a single v_add_f32_dpp (no LDS pipe).
template<int CTRL>
__device__ __forceinline__ float dpp_add(float x) {
  int mv = __builtin_amdgcn_update_dpp(0, __float_as_int(x), CTRL, 0xF, 0xF, true);
  return x + __int_as_float(mv);
}
// Sum across a 16-lane DPP row: quad_perm xor1 (0xB1), xor2 (0x4E), row_ror:4, row_ror:8.
__device__ __forceinline__ float row16_sum(float x) {
  x = dpp_add<0xB1>(x);
  x = dpp_add<0x4E>(x);
  x = dpp_add<0x124>(x);
  x = dpp_add<0x128>(x);
  return x;
}

__device__ __forceinline__ unsigned short f2bf_rne(float x) {
  unsigned u = __float_as_uint(x);
  u += 0x7FFFu + ((u >> 16) & 1u);
  return (unsigned short)(u >> 16);
}

struct Frag {
  float q[4][4], k[4][4], v[4][4];
};

__device__ __forceinline__ void load_frag(Frag& f, const float* __restrict__ qb,
                                          int j) {
#pragma unroll
  for (int m = 0; m < 4; ++m) {
    const float* rp = qb + (size_t)(m * 2048 + j) * ROW;
    float4 t;
    t = *(const float4*)(rp);
    f.q[m][0] = t.x; f.q[m][1] = t.y; f.q[m][2] = t.z; f.q[m][3] = t.w;
    t = *(const float4*)(rp + 1024);
    f.k[m][0] = t.x; f.k[m][1] = t.y; f.k[m][2] = t.z; f.k[m][3] = t.w;
    t = *(const float4*)(rp + 2048);
    f.v[m][0] = t.x; f.v[m][1] = t.y; f.v[m][2] = t.z; f.v[m][3] = t.w;
  }
}

template<bool USE_BF16>
__device__ __forceinline__ void compute_frag(const Frag& f, int j, size_t obase,
                                             float* __restrict__ out,
                                             unsigned short* __restrict__ ws16,
                                             float* cs) {
  // 4x4 scores: per-lane d-quad partial, DPP 16-lane reduce.
  float S[4][4];
#pragma unroll
  for (int m = 0; m < 4; ++m)
#pragma unroll
    for (int m2 = 0; m2 < 4; ++m2) {
      float s = f.q[m][0] * f.k[m2][0] + f.q[m][1] * f.k[m2][1] +
                f.q[m][2] * f.k[m2][2] + f.q[m][3] * f.k[m2][3];
      S[m][m2] = row16_sum(s) * 0.125f;   // 1/sqrt(64)
    }

  float acc[4][4];

  // branch 1 (r=1): softmax over 4 keys, every position.
#pragma unroll
  for (int m = 0; m < 4; ++m) {
    float mx = fmaxf(fmaxf(S[m][0], S[m][1]), fmaxf(S[m][2], S[m][3]));
    float e0 = __expf(S[m][0] - mx);
    float e1 = __expf(S[m][1] - mx);
    float e2 = __expf(S[m][2] - mx);
    float e3 = __expf(S[m][3] - mx);
    float inv = 1.0f / (e0 + e1 + e2 + e3);
    e0 *= inv; e1 *= inv; e2 *= inv; e3 *= inv;
#pragma unroll
    for (int c = 0; c < 4; ++c)
      acc[m][c] = e0 * f.v[0][c] + e1 * f.v[1][c] +
                  e2 * f.v[2][c] + e3 * f.v[3][c];
  }

  // branch 2 (r=2): iff j even (block-uniform).
  if ((j & 1) == 0) {
#pragma unroll
    for (int m = 0; m < 4; ++m) {
      const int a  = m & 1;
      const int b2 = a + 2;
      float sa = S[m][a], sb = S[m][b2];
      float mx = fmaxf(sa, sb);
      float ea = __expf(sa - mx);
      float eb = __expf(sb - mx);
      float inv = 1.0f / (ea + eb);
      ea *= inv; eb *= inv;
#pragma unroll
      for (int c = 0; c < 4; ++c)
        acc[m][c] += ea * f.v[a][c] + eb * f.v[b2][c];
    }
  }

  // branch 3 (r=4): iff j % 4 == 0 (block-uniform).
  if ((j & 3) == 0) {
#pragma unroll
    for (int m = 0; m < 4; ++m)
#pragma unroll
      for (int c = 0; c < 4; ++c)
        acc[m][c] += f.v[m][c];
  }

  // store unnormalized; accumulate colsum partials in registers.
#pragma unroll
  for (int m = 0; m < 4; ++m) {
    const size_t oi = obase + (size_t)(m * 2048 + j) * OUT_N;
    if (USE_BF16) {
      ushort4 st;
      st.x = f2bf_rne(acc[m][0]); st.y = f2bf_rne(acc[m][1]);
      st.z = f2bf_rne(acc[m][2]); st.w = f2bf_rne(acc[m][3]);
      *(ushort4*)(ws16 + oi) = st;
    } else {
      *(float4*)(out + oi) =
          make_float4(acc[m][0], acc[m][1], acc[m][2], acc[m][3]);
    }
    cs[0] += acc[m][0]; cs[1] += acc[m][1];
    cs[2] += acc[m][2]; cs[3] += acc[m][3];
  }
}

// Kernel 1: block = (b, chunk of 4 consecutive j), all 16 heads; NO LDS;
// 2-deep software pipeline; NO ATOMICS — per-block colsum partials are
// written non-atomically as one contiguous 4 KB float4 store.
template<bool USE_BF16>
__global__ __launch_bounds__(256) void dil_main(const float* __restrict__ qkv,
                                                float* __restrict__ out,
                                                unsigned short* __restrict__ ws16,
                                                float* __restrict__ partial) {
  const int tid  = threadIdx.x;
  const int bid  = blockIdx.x;        // 0..2047
  const int b    = bid >> 9;
  const int j0   = (bid & 511) * 4;   // first of 4 consecutive j

  const float* qb = qkv + (size_t)b * QKV_B + tid * 4;
  const size_t obase = (size_t)b * OUT_B + tid * 4;

  float cs[4] = {0.f, 0.f, 0.f, 0.f};

  Frag A, B;
  load_frag(A, qb, j0);                    // it 0
  load_frag(B, qb, j0 + 1);                // it 1 (in flight during compute 0)
  compute_frag<USE_BF16>(A, j0, obase, out, ws16, cs);
  load_frag(A, qb, j0 + 2);                // it 2
  compute_frag<USE_BF16>(B, j0 + 1, obase, out, ws16, cs);
  load_frag(B, qb, j0 + 3);                // it 3
  compute_frag<USE_BF16>(A, j0 + 2, obase, out, ws16, cs);
  compute_frag<USE_BF16>(B, j0 + 3, obase, out, ws16, cs);

  // partial[bid][tid*4 .. tid*4+3]  — block writes 4 KB contiguous.
  *(float4*)(partial + (size_t)bid * 1024 + tid * 4) =
      make_float4(cs[0], cs[1], cs[2], cs[3]);
}

// Kernel 2: deterministic f64 tree-sum of the 512 per-block partials for
// each of the 4096 (b,h,d) columns, then reciprocal.
// LATENCY FIX vs R7: 8 independent accumulator chains + 8 loads in flight
// (was: 512 serial dependent load->add iterations = exposed L2 latency).
__global__ __launch_bounds__(256) void dil_recip(const float* __restrict__ partial,
                                                 float* __restrict__ recip) {
  const int i = blockIdx.x * 256 + threadIdx.x;   // 0..4095
  const int b = i >> 10;
  const int w = i & 1023;
  const float* p = partial + (size_t)b * BLKS_PER_B * 1024 + w;
  double s0 = 0.0, s1 = 0.0, s2 = 0.0, s3 = 0.0;
  double s4 = 0.0, s5 = 0.0, s6 = 0.0, s7 = 0.0;
  for (int r = 0; r < BLKS_PER_B; r += 8) {
    // 8 independent loads issued back-to-back, then 8 independent adds.
    float f0 = p[(size_t)(r + 0) * 1024];
    float f1 = p[(size_t)(r + 1) * 1024];
    float f2 = p[(size_t)(r + 2) * 1024];
    float f3 = p[(size_t)(r + 3) * 1024];
    float f4 = p[(size_t)(r + 4) * 1024];
    float f5 = p[(size_t)(r + 5) * 1024];
    float f6 = p[(size_t)(r + 6) * 1024];
    float f7 = p[(size_t)(r + 7) * 1024];
    s0 += (double)f0; s1 += (double)f1; s2 += (double)f2; s3 += (double)f3;
    s4 += (double)f4; s5 += (double)f5; s6 += (double)f6; s7 += (double)f7;
  }
  double s = ((s0 + s1) + (s2 + s3)) + ((s4 + s5) + (s6 + s7));
  recip[i] = (float)(1.0 / s);
}

// Kernel 3a: bf16 staging -> normalized f32 out. Thread handles 8 elems.
__global__ __launch_bounds__(256) void dil_scale_bf16(const unsigned short* __restrict__ ws16,
                                                      float* __restrict__ out,
                                                      const float* __restrict__ recip) {
  const long long u = (long long)blockIdx.x * 256 + threadIdx.x;
  const long long e = u * 8;
  const int b  = (int)(e >> 23);
  const int h  = (int)((e >> 6) & 15);
  const int q8 = (int)((e >> 3) & 7);    // which d-octet

  const float4 r0 = ((const float4*)recip)[((b * 16 + h) << 4) + q8 * 2];
  const float4 r1 = ((const float4*)recip)[((b * 16 + h) << 4) + q8 * 2 + 1];

  const v4u raw = __builtin_nontemporal_load((const v4u*)(ws16 + e));
  v4f o0, o1;
  o0[0] = __uint_as_float((raw[0] & 0xFFFFu) << 16) * r0.x;
  o0[1] = __uint_as_float((raw[0] & 0xFFFF0000u))   * r0.y;
  o0[2] = __uint_as_float((raw[1] & 0xFFFFu) << 16) * r0.z;
  o0[3] = __uint_as_float((raw[1] & 0xFFFF0000u))   * r0.w;
  o1[0] = __uint_as_float((raw[2] & 0xFFFFu) << 16) * r1.x;
  o1[1] = __uint_as_float((raw[2] & 0xFFFF0000u))   * r1.y;
  o1[2] = __uint_as_float((raw[3] & 0xFFFFu) << 16) * r1.z;
  o1[3] = __uint_as_float((raw[3] & 0xFFFF0000u))   * r1.w;
  __builtin_nontemporal_store(o0, (v4f*)(out + e));
  __builtin_nontemporal_store(o1, (v4f*)(out + e + 4));
}

// Kernel 3b (fallback): in-place f32 scale
__global__ __launch_bounds__(256) void dil_scale_f32(float* __restrict__ out,
                                                     const float* __restrict__ recip) {
  const long long f = (long long)blockIdx.x * 256 + threadIdx.x;  // float4 index
  const int d4 = (int)(f & 15);
  const int h  = (int)((f >> 4) & 15);
  const int b  = (int)(f >> 21);
  const float4 r = ((const float4*)recip)[(b * 16 + h) * 16 + d4];
  float4 o = ((const float4*)out)[f];
  o.x *= r.x; o.y *= r.y; o.z *= r.z; o.w *= r.w;
  ((float4*)out)[f] = o;
}

extern "C" void kernel_launch(void* const* d_in, const int* in_sizes, int n_in,
                              void* d_out, int out_size, void* d_ws, size_t ws_size,
                              hipStream_t stream) {
  const float* qkv = (const float*)d_in[0];
  float* out = (float*)d_out;

  const size_t bf16_bytes    = (size_t)OUT_TOT * 2;            // 67108864
  const size_t partial_bytes = (size_t)NBLK * 1024 * 4;        // 8388608
  const size_t recip_bytes   = 4096 * sizeof(float);

  bool use_bf16 = (bf16_bytes + partial_bytes + recip_bytes) <= ws_size;

  unsigned short* ws16 = (unsigned short*)d_ws;
  char* tail = (char*)d_ws + (use_bf16 ? bf16_bytes : 0);
  float* partial = (float*)tail;
  float* recip   = (float*)(tail + partial_bytes);

  if (use_bf16)
    dil_main<true><<<NBLK, 256, 0, stream>>>(qkv, out, ws16, partial);
  else
    dil_main<false><<<NBLK, 256, 0, stream>>>(qkv, out, ws16, partial);

  dil_recip<<<16, 256, 0, stream>>>(partial, recip);

  if (use_bf16) {
    const long long nu = OUT_TOT / 8;              // 4194304 threads
    dil_scale_bf16<<<(int)(nu / 256), 256, 0, stream>>>(ws16, out, recip);
  } else {
    const long long nf4 = OUT_TOT / 4;
    dil_scale_f32<<<(int)(nf4 / 256), 256, 0, stream>>>(out, recip);
  }
}

// Round 10
// 150.030 us; speedup vs baseline: 2.7835x; 1.0140x over previous
//
#include <hip/hip_runtime.h>

// qkv: (4, 8192, 3, 16, 64) f32 ; out: (4, 8192, 16, 64) f32
constexpr int   Bn    = 4;
constexpr int   Nn    = 8192;
constexpr int   Hn    = 16;
constexpr int   Dn    = 64;
constexpr int   ROW   = 3 * Hn * Dn;                   // 3072 floats = 12 KB
constexpr long long QKV_B = (long long)Nn * ROW;       // 25165824
constexpr int   OUT_N = Hn * Dn;                       // 1024
constexpr long long OUT_B = (long long)Nn * OUT_N;     // 8388608
constexpr long long OUT_TOT = (long long)Bn * OUT_B;   // 33554432
constexpr int   NBLK  = 2048;                          // dil_main grid
constexpr int   BLKS_PER_B = 512;

using v4f = __attribute__((ext_vector_type(4))) float;
using v4u = __attribute__((ext_vector_type(4))) unsigned int;

// x + dpp_move(x): fuses to a single v_add_f32_dpp (no LDS pipe).
template<int CTRL>
__device__ __forceinline__ float dpp_add(float x) {
  int mv = __builtin_amdgcn_update_dpp(0, __float_as_int(x), CTRL, 0xF, 0xF, true);
  return x + __int_as_float(mv);
}
// Sum across a 16-lane DPP row: quad_perm xor1 (0xB1), xor2 (0x4E), row_ror:4, row_ror:8.
__device__ __forceinline__ float row16_sum(float x) {
  x = dpp_add<0xB1>(x);
  x = dpp_add<0x4E>(x);
  x = dpp_add<0x124>(x);
  x = dpp_add<0x128>(x);
  return x;
}

__device__ __forceinline__ unsigned short f2bf_rne(float x) {
  unsigned u = __float_as_uint(x);
  u += 0x7FFFu + ((u >> 16) & 1u);
  return (unsigned short)(u >> 16);
}

struct Frag {
  float q[4][4], k[4][4], v[4][4];
};

__device__ __forceinline__ void load_frag(Frag& f, const float* __restrict__ qb,
                                          int j) {
#pragma unroll
  for (int m = 0; m < 4; ++m) {
    const float* rp = qb + (size_t)(m * 2048 + j) * ROW;
    float4 t;
    t = *(const float4*)(rp);
    f.q[m][0] = t.x; f.q[m][1] = t.y; f.q[m][2] = t.z; f.q[m][3] = t.w;
    t = *(const float4*)(rp + 1024);
    f.k[m][0] = t.x; f.k[m][1] = t.y; f.k[m][2] = t.z; f.k[m][3] = t.w;
    t = *(const float4*)(rp + 2048);
    f.v[m][0] = t.x; f.v[m][1] = t.y; f.v[m][2] = t.z; f.v[m][3] = t.w;
  }
}

template<bool USE_BF16>
__device__ __forceinline__ void compute_frag(const Frag& f, int j, size_t obase,
                                             float* __restrict__ out,
                                             unsigned short* __restrict__ ws16,
                                             float* cs) {
  // 4x4 scores: per-lane d-quad partial, DPP 16-lane reduce.
  float S[4][4];
#pragma unroll
  for (int m = 0; m < 4; ++m)
#pragma unroll
    for (int m2 = 0; m2 < 4; ++m2) {
      float s = f.q[m][0] * f.k[m2][0] + f.q[m][1] * f.k[m2][1] +
                f.q[m][2] * f.k[m2][2] + f.q[m][3] * f.k[m2][3];
      S[m][m2] = row16_sum(s) * 0.125f;   // 1/sqrt(64)
    }

  float acc[4][4];

  // branch 1 (r=1): softmax over 4 keys, every position.
#pragma unroll
  for (int m = 0; m < 4; ++m) {
    float mx = fmaxf(fmaxf(S[m][0], S[m][1]), fmaxf(S[m][2], S[m][3]));
    float e0 = __expf(S[m][0] - mx);
    float e1 = __expf(S[m][1] - mx);
    float e2 = __expf(S[m][2] - mx);
    float e3 = __expf(S[m][3] - mx);
    float inv = 1.0f / (e0 + e1 + e2 + e3);
    e0 *= inv; e1 *= inv; e2 *= inv; e3 *= inv;
#pragma unroll
    for (int c = 0; c < 4; ++c)
      acc[m][c] = e0 * f.v[0][c] + e1 * f.v[1][c] +
                  e2 * f.v[2][c] + e3 * f.v[3][c];
  }

  // branch 2 (r=2): iff j even (block-uniform).
  if ((j & 1) == 0) {
#pragma unroll
    for (int m = 0; m < 4; ++m) {
      const int a  = m & 1;
      const int b2 = a + 2;
      float sa = S[m][a], sb = S[m][b2];
      float mx = fmaxf(sa, sb);
      float ea = __expf(sa - mx);
      float eb = __expf(sb - mx);
      float inv = 1.0f / (ea + eb);
      ea *= inv; eb *= inv;
#pragma unroll
      for (int c = 0; c < 4; ++c)
        acc[m][c] += ea * f.v[a][c] + eb * f.v[b2][c];
    }
  }

  // branch 3 (r=4): iff j % 4 == 0 (block-uniform).
  if ((j & 3) == 0) {
#pragma unroll
    for (int m = 0; m < 4; ++m)
#pragma unroll
      for (int c = 0; c < 4; ++c)
        acc[m][c] += f.v[m][c];
  }

  // store unnormalized; accumulate colsum partials in registers.
#pragma unroll
  for (int m = 0; m < 4; ++m) {
    const size_t oi = obase + (size_t)(m * 2048 + j) * OUT_N;
    if (USE_BF16) {
      ushort4 st;
      st.x = f2bf_rne(acc[m][0]); st.y = f2bf_rne(acc[m][1]);
      st.z = f2bf_rne(acc[m][2]); st.w = f2bf_rne(acc[m][3]);
      *(ushort4*)(ws16 + oi) = st;
    } else {
      *(float4*)(out + oi) =
          make_float4(acc[m][0], acc[m][1], acc[m][2], acc[m][3]);
    }
    cs[0] += acc[m][0]; cs[1] += acc[m][1];
    cs[2] += acc[m][2]; cs[3] += acc[m][3];
  }
}

// Kernel 1: block = (b, chunk of 4 consecutive j), all 16 heads; NO LDS;
// 2-deep software pipeline FORCED via sched_barrier(0): without the pins,
// hipcc sinks the prefetch loads to just-before-use (R8 showed VGPR=40,
// impossible for a held double-buffer), deleting the pipeline.
template<bool USE_BF16>
__global__ __launch_bounds__(256) void dil_main(const float* __restrict__ qkv,
                                                float* __restrict__ out,
                                                unsigned short* __restrict__ ws16,
                                                float* __restrict__ partial) {
  const int tid  = threadIdx.x;
  const int bid  = blockIdx.x;        // 0..2047
  const int b    = bid >> 9;
  const int j0   = (bid & 511) * 4;   // first of 4 consecutive j

  const float* qb = qkv + (size_t)b * QKV_B + tid * 4;
  const size_t obase = (size_t)b * OUT_B + tid * 4;

  float cs[4] = {0.f, 0.f, 0.f, 0.f};

  Frag A, B;
  load_frag(A, qb, j0);                    // it 0
  load_frag(B, qb, j0 + 1);                // it 1
  __builtin_amdgcn_sched_barrier(0);       // 24 loads issued before any compute
  compute_frag<USE_BF16>(A, j0, obase, out, ws16, cs);
  load_frag(A, qb, j0 + 2);                // it 2 (interleaves with compute 0)
  __builtin_amdgcn_sched_barrier(0);
  compute_frag<USE_BF16>(B, j0 + 1, obase, out, ws16, cs);
  load_frag(B, qb, j0 + 3);                // it 3 (interleaves with compute 1)
  __builtin_amdgcn_sched_barrier(0);
  compute_frag<USE_BF16>(A, j0 + 2, obase, out, ws16, cs);
  compute_frag<USE_BF16>(B, j0 + 3, obase, out, ws16, cs);

  // partial[bid][tid*4 .. tid*4+3]  — block writes 4 KB contiguous.
  *(float4*)(partial + (size_t)bid * 1024 + tid * 4) =
      make_float4(cs[0], cs[1], cs[2], cs[3]);
}

// Kernel 2: deterministic f64 tree-sum of the 512 per-block partials for
// each of the 4096 (b,h,d) columns, then reciprocal. 8 independent chains.
__global__ __launch_bounds__(256) void dil_recip(const float* __restrict__ partial,
                                                 float* __restrict__ recip) {
  const int i = blockIdx.x * 256 + threadIdx.x;   // 0..4095
  const int b = i >> 10;
  const int w = i & 1023;
  const float* p = partial + (size_t)b * BLKS_PER_B * 1024 + w;
  double s0 = 0.0, s1 = 0.0, s2 = 0.0, s3 = 0.0;
  double s4 = 0.0, s5 = 0.0, s6 = 0.0, s7 = 0.0;
  for (int r = 0; r < BLKS_PER_B; r += 8) {
    float f0 = p[(size_t)(r + 0) * 1024];
    float f1 = p[(size_t)(r + 1) * 1024];
    float f2 = p[(size_t)(r + 2) * 1024];
    float f3 = p[(size_t)(r + 3) * 1024];
    float f4 = p[(size_t)(r + 4) * 1024];
    float f5 = p[(size_t)(r + 5) * 1024];
    float f6 = p[(size_t)(r + 6) * 1024];
    float f7 = p[(size_t)(r + 7) * 1024];
    s0 += (double)f0; s1 += (double)f1; s2 += (double)f2; s3 += (double)f3;
    s4 += (double)f4; s5 += (double)f5; s6 += (double)f6; s7 += (double)f7;
  }
  double s = ((s0 + s1) + (s2 + s3)) + ((s4 + s5) + (s6 + s7));
  recip[i] = (float)(1.0 / s);
}

// Kernel 3a: bf16 staging -> normalized f32 out. Thread handles 8 elems.
// ws16 was just written and fits L3 -> use a NORMAL (cacheable) load;
// out is never re-read -> nontemporal store.
__global__ __launch_bounds__(256) void dil_scale_bf16(const unsigned short* __restrict__ ws16,
                                                      float* __restrict__ out,
                                                      const float* __restrict__ recip) {
  const long long u = (long long)blockIdx.x * 256 + threadIdx.x;
  const long long e = u * 8;
  const int b  = (int)(e >> 23);
  const int h  = (int)((e >> 6) & 15);
  const int q8 = (int)((e >> 3) & 7);    // which d-octet

  const float4 r0 = ((const float4*)recip)[((b * 16 + h) << 4) + q8 * 2];
  const float4 r1 = ((const float4*)recip)[((b * 16 + h) << 4) + q8 * 2 + 1];

  const uint4 raw = *(const uint4*)(ws16 + e);
  v4f o0, o1;
  o0[0] = __uint_as_float((raw.x & 0xFFFFu) << 16) * r0.x;
  o0[1] = __uint_as_float((raw.x & 0xFFFF0000u))   * r0.y;
  o0[2] = __uint_as_float((raw.y & 0xFFFFu) << 16) * r0.z;
  o0[3] = __uint_as_float((raw.y & 0xFFFF0000u))   * r0.w;
  o1[0] = __uint_as_float((raw.z & 0xFFFFu) << 16) * r1.x;
  o1[1] = __uint_as_float((raw.z & 0xFFFF0000u))   * r1.y;
  o1[2] = __uint_as_float((raw.w & 0xFFFFu) << 16) * r1.z;
  o1[3] = __uint_as_float((raw.w & 0xFFFF0000u))   * r1.w;
  __builtin_nontemporal_store(o0, (v4f*)(out + e));
  __builtin_nontemporal_store(o1, (v4f*)(out + e + 4));
}

// Kernel 3b (fallback): in-place f32 scale
__global__ __launch_bounds__(256) void dil_scale_f32(float* __restrict__ out,
                                                     const float* __restrict__ recip) {
  const long long f = (long long)blockIdx.x * 256 + threadIdx.x;  // float4 index
  const int d4 = (int)(f & 15);
  const int h  = (int)((f >> 4) & 15);
  const int b  = (int)(f >> 21);
  const float4 r = ((const float4*)recip)[(b * 16 + h) * 16 + d4];
  float4 o = ((const float4*)out)[f];
  o.x *= r.x; o.y *= r.y; o.z *= r.z; o.w *= r.w;
  ((float4*)out)[f] = o;
}

extern "C" void kernel_launch(void* const* d_in, const int* in_sizes, int n_in,
                              void* d_out, int out_size, void* d_ws, size_t ws_size,
                              hipStream_t stream) {
  const float* qkv = (const float*)d_in[0];
  float* out = (float*)d_out;

  const size_t bf16_bytes    = (size_t)OUT_TOT * 2;            // 67108864
  const size_t partial_bytes = (size_t)NBLK * 1024 * 4;        // 8388608
  const size_t recip_bytes   = 4096 * sizeof(float);

  bool use_bf16 = (bf16_bytes + partial_bytes + recip_bytes) <= ws_size;

  unsigned short* ws16 = (unsigned short*)d_ws;
  char* tail = (char*)d_ws + (use_bf16 ? bf16_bytes : 0);
  float* partial = (float*)tail;
  float* recip   = (float*)(tail + partial_bytes);

  if (use_bf16)
    dil_main<true><<<NBLK, 256, 0, stream>>>(qkv, out, ws16, partial);
  else
    dil_main<false><<<NBLK, 256, 0, stream>>>(qkv, out, ws16, partial);

  dil_recip<<<16, 256, 0, stream>>>(partial, recip);

  if (use_bf16) {
    const long long nu = OUT_TOT / 8;              // 4194304 threads
    dil_scale_bf16<<<(int)(nu / 256), 256, 0, stream>>>(ws16, out, recip);
  } else {
    const long long nf4 = OUT_TOT / 4;
    dil_scale_f32<<<(int)(nf4 / 256), 256, 0, stream>>>(out, recip);
  }
}